// Round 3
// baseline (698.299 us; speedup 1.0000x reference)
//
#include <hip/hip_runtime.h>
#include <hip/hip_bf16.h>
#include <stdint.h>

// R3: full-line weight staging (d-tile 16), direct-global A-fragments (no A LDS),
// LDS hoisted to kernel scope (R2 bug: __shared__ inside twice-inlined impl doubled LDS).
// Block = (dg d-tile, og o-tile 32, bg b-tile 32, ksid); 4 waves <-> 4 d each (DPW).
// W tile LDS: [plane=(d_loc*2+t)][o 32][c 16 pad 20], plane stride 644 u16 (bank-spread).
// l1,l2 direct bf16 out; l3..l7 atomic fp32 S + fin; l8,l9 R2 tail; epi unchanged.

#define B_   128
#define H_   256
#define OUT_ 10
#define WT_PLANE 644          // u16 per (d,t) plane: 32*20 + 4 (8B-aligned, bank-shift 2)
#define WT_ELEMS (32*WT_PLANE) // 20608 u16 = 41216 B

typedef __attribute__((ext_vector_type(4))) float floatx4;
typedef __attribute__((ext_vector_type(8))) short shortx8;
typedef __attribute__((ext_vector_type(4))) short shortx4;

__device__ __forceinline__ float bf2f(unsigned short u){
    union { unsigned int u; float f; } c; c.u = ((unsigned int)u) << 16; return c.f;
}
__device__ __forceinline__ unsigned short f2bf(float f){
    union { float f; unsigned int u; } c; c.f = f;
    unsigned int x = c.u;
    x += 0x7FFFu + ((x >> 16) & 1u);
    return (unsigned short)(x >> 16);
}

// ---------------------------------------------------------------------------
__global__ void probe_kernel(const unsigned int* __restrict__ x, int* __restrict__ flag){
    __shared__ int cnt[256];
    int tid = threadIdx.x;
    unsigned short lo = (unsigned short)(x[tid] & 0xFFFFu);
    int e = (lo >> 7) & 0xFF;
    cnt[tid] = (e >= 90 && e <= 143) ? 1 : 0;
    __syncthreads();
    for (int s = 128; s > 0; s >>= 1){
        if (tid < s) cnt[tid] += cnt[tid + s];
        __syncthreads();
    }
    if (tid == 0) *flag = (cnt[0] > 160) ? 1 : 0;
}

// ---------------------------------------------------------------------------
// Layer 0: A1[p=d][b][o] = relu(sum_{c,t} x[b,c,2d+t]*w0[o,c,d,t]) * (1/sqrt(3))
__global__ __launch_bounds__(256) void l0_kernel(const int* __restrict__ flag,
        const void* __restrict__ xv, const void* __restrict__ wv,
        unsigned short* __restrict__ A1){
    __shared__ float Xs[128*6];
    const int d = blockIdx.x;
    const int tid = threadIdx.x;
    const bool BF = (*flag != 0);
    for (int i = tid; i < 384; i += 256){
        int b = i / 3, c = i - b*3;
        if (BF){
            unsigned int u = *(const unsigned int*)((const unsigned short*)xv + (b*3+c)*1024 + 2*d);
            Xs[b*6 + c*2]     = bf2f((unsigned short)(u & 0xFFFFu));
            Xs[b*6 + c*2 + 1] = bf2f((unsigned short)(u >> 16));
        } else {
            const float* xf = (const float*)xv + (b*3+c)*1024 + 2*d;
            Xs[b*6 + c*2] = xf[0]; Xs[b*6 + c*2 + 1] = xf[1];
        }
    }
    __syncthreads();
    const int o = tid;
    float wr[6];
    #pragma unroll
    for (int c = 0; c < 3; ++c){
        if (BF){
            unsigned int u = *(const unsigned int*)((const unsigned short*)wv + ((o*3+c)*512 + d)*2);
            wr[c*2]   = bf2f((unsigned short)(u & 0xFFFFu));
            wr[c*2+1] = bf2f((unsigned short)(u >> 16));
        } else {
            const float* wf = (const float*)wv + ((o*3+c)*512 + d)*2;
            wr[c*2] = wf[0]; wr[c*2+1] = wf[1];
        }
    }
    const float s3 = 0.57735026918962576f;
    for (int b = 0; b < 128; ++b){
        float s = 0.f;
        #pragma unroll
        for (int j = 0; j < 6; ++j) s += Xs[b*6 + j] * wr[j];
        A1[d*32768 + b*256 + o] = f2bf(fmaxf(s, 0.f) * s3);
    }
}

// ---------------------------------------------------------------------------
// Main layer: DPW d's per wave (DT=4*DPW per block). K=32 MFMA, k = t*16 + c.
template<int DPW, bool WBF, bool ATOMIC>
__device__ __forceinline__ void layer3_impl(unsigned short* __restrict__ Wt,
        const unsigned short* __restrict__ Ain, const void* __restrict__ wv,
        void* __restrict__ out, int dl, int dgN, int TS){
    constexpr int DT = 4*DPW;
    const int tid = threadIdx.x;
    const int lane = tid & 63, wv_ = tid >> 6;
    const int mr = lane & 15, g = lane >> 4;
    const int tI = g >> 1, chI = g & 1;
    int bi = blockIdx.x;
    const int bg = bi & 3; const int og = (bi >> 2) & 7; const int rest = bi >> 5;
    const int dg = rest % dgN; const int ksid = rest / dgN;
    const int d0 = dg * DT, o0 = og * 32, b0 = bg * 32;
    const float* wF = (const float*)wv;
    const unsigned short* wB = (const unsigned short*)wv;

    floatx4 acc[2][2][DPW];
    #pragma unroll
    for (int m = 0; m < 2; ++m)
        #pragma unroll
        for (int nb = 0; nb < 2; ++nb)
            #pragma unroll
            for (int dd = 0; dd < DPW; ++dd)
                acc[m][nb][dd] = (floatx4){0.f,0.f,0.f,0.f};

    for (int s = 0; s < TS; ++s){
        const int c0 = (ksid*TS + s) << 4;
        // ---- stage W: 32 o x 16 c runs, contiguous (d,t) 16B parts, transpose to LDS
        if (WBF){
            constexpr int PARTS = DT/4;              // 16B = 8 bf16 = 4 d x 2 t
            for (int task = tid; task < 512*PARTS; task += 256){
                int part = (PARTS == 1) ? 0 : (task & (PARTS-1));
                int run  = (PARTS == 1) ? task : (task / PARTS);
                int cl = run & 15, ol = run >> 4;
                const unsigned short* src = wB + ((size_t)((o0+ol)*256 + c0+cl)*dl + d0)*2 + part*8;
                uint4 u = *(const uint4*)src;
                const unsigned short* e = (const unsigned short*)&u;
                #pragma unroll
                for (int j = 0; j < 8; ++j){
                    int dloc = part*4 + (j >> 1), t = j & 1;
                    Wt[(dloc*2 + t)*WT_PLANE + ol*20 + cl] = e[j];
                }
            }
        } else {
            constexpr int PARTS = DT/2;              // 16B = 4 fp32 = 2 d x 2 t
            for (int task = tid; task < 512*PARTS; task += 256){
                int part = task & (PARTS-1);
                int run  = task / PARTS;
                int cl = run & 15, ol = run >> 4;
                const float* src = wF + ((size_t)((o0+ol)*256 + c0+cl)*dl + d0)*2 + part*4;
                float4 v = *(const float4*)src;
                int base = (part*4)*WT_PLANE + ol*20 + cl;
                Wt[base]              = f2bf(v.x);
                Wt[base + WT_PLANE]   = f2bf(v.y);
                Wt[base + 2*WT_PLANE] = f2bf(v.z);
                Wt[base + 3*WT_PLANE] = f2bf(v.w);
            }
        }
        __syncthreads();
        // ---- A frags direct from global (16B contiguous per lane)
        shortx8 af[2][DPW];
        #pragma unroll
        for (int m = 0; m < 2; ++m)
            #pragma unroll
            for (int dd = 0; dd < DPW; ++dd){
                int d = d0 + wv_*DPW + dd;
                int p = 2*d + tI;
                const unsigned short* ap = Ain + ((size_t)p*128 + b0 + m*16 + mr)*256 + c0 + chI*8;
                uint4 u = *(const uint4*)ap;
                af[m][dd] = *(const shortx8*)&u;
            }
        // ---- B frags from LDS (two 8B reads, 40B row stride: conflict-free)
        shortx8 bfr[2][DPW];
        #pragma unroll
        for (int nb = 0; nb < 2; ++nb)
            #pragma unroll
            for (int dd = 0; dd < DPW; ++dd){
                int off = ((wv_*DPW + dd)*2 + tI)*WT_PLANE + (nb*16 + mr)*20 + chI*8;
                shortx4 lo = *(const shortx4*)(Wt + off);
                shortx4 hi = *(const shortx4*)(Wt + off + 4);
                shortx8 bb;
                bb[0]=lo[0]; bb[1]=lo[1]; bb[2]=lo[2]; bb[3]=lo[3];
                bb[4]=hi[0]; bb[5]=hi[1]; bb[6]=hi[2]; bb[7]=hi[3];
                bfr[nb][dd] = bb;
            }
        #pragma unroll
        for (int m = 0; m < 2; ++m)
            #pragma unroll
            for (int nb = 0; nb < 2; ++nb)
                #pragma unroll
                for (int dd = 0; dd < DPW; ++dd)
                    acc[m][nb][dd] = __builtin_amdgcn_mfma_f32_16x16x32_bf16(af[m][dd], bfr[nb][dd], acc[m][nb][dd], 0,0,0);
        __syncthreads();
    }
    // ---- epilogue: D row g*4+r -> b, col mr -> o
    #pragma unroll
    for (int m = 0; m < 2; ++m)
        #pragma unroll
        for (int dd = 0; dd < DPW; ++dd){
            int d = d0 + wv_*DPW + dd;
            #pragma unroll
            for (int nb = 0; nb < 2; ++nb){
                int o = o0 + nb*16 + mr;
                #pragma unroll
                for (int r = 0; r < 4; ++r){
                    int b = b0 + m*16 + g*4 + r;
                    size_t idx = ((size_t)d*128 + b)*256 + o;
                    float v = acc[m][nb][dd][r];
                    if (ATOMIC) unsafeAtomicAdd((float*)out + idx, v);
                    else ((unsigned short*)out)[idx] = f2bf(fmaxf(v, 0.f) * 0.0625f);
                }
            }
        }
}

template<int DPW, bool ATOMIC>
__global__ __launch_bounds__(256,3) void layer3_k(const int* __restrict__ flag,
        const unsigned short* __restrict__ Ain, const void* __restrict__ wv,
        void* __restrict__ out, int dl, int dgN, int TS){
    __shared__ unsigned short Wt[WT_ELEMS];
    if (*flag) layer3_impl<DPW, true,  ATOMIC>(Wt, Ain, wv, out, dl, dgN, TS);
    else       layer3_impl<DPW, false, ATOMIC>(Wt, Ain, wv, out, dl, dgN, TS);
}

// ---------------------------------------------------------------------------
// Tail layers (dl<=2): gather (weights <=1MB, L2-resident), atomic fp32 out.
template<bool WBF>
__device__ __forceinline__ void tail_impl(const unsigned short* __restrict__ Ain,
        const void* __restrict__ wv, float* __restrict__ outS, int dl, int ksplit){
    int id = blockIdx.x;
    int d = id % dl; int t2 = id / dl;
    int ob = t2 & 3; int ksid = t2 >> 2;
    const int KSEG = 512 / ksplit;
    const int k0s = ksid * KSEG;
    const int lane = threadIdx.x & 63, wv2 = threadIdx.x >> 6;
    const int mr = lane & 15, kg = lane >> 4;
    const float* wF = (const float*)wv;
    const unsigned short* wB = (const unsigned short*)wv;
    floatx4 acc[2][4];
    #pragma unroll
    for (int mi = 0; mi < 2; ++mi)
        #pragma unroll
        for (int ni = 0; ni < 4; ++ni) acc[mi][ni] = (floatx4){0.f,0.f,0.f,0.f};
    for (int k0 = k0s; k0 < k0s + KSEG; k0 += 32){
        int c0 = (k0 >> 1) + kg*4;
        shortx8 af[2];
        #pragma unroll
        for (int mi = 0; mi < 2; ++mi){
            int b = wv2*32 + mi*16 + mr;
            #pragma unroll
            for (int cc = 0; cc < 4; ++cc){
                af[mi][2*cc]   = (short)Ain[(2*d)*32768   + b*256 + c0 + cc];
                af[mi][2*cc+1] = (short)Ain[(2*d+1)*32768 + b*256 + c0 + cc];
            }
        }
        shortx8 bf_[4];
        #pragma unroll
        for (int ni = 0; ni < 4; ++ni){
            int o = ob*64 + ni*16 + mr;
            int base = ((o*256 + c0)*dl + d)*2;
            #pragma unroll
            for (int cc = 0; cc < 4; ++cc){
                if (WBF){
                    unsigned int u = *(const unsigned int*)(wB + base);
                    bf_[ni][2*cc]   = (short)(u & 0xFFFFu);
                    bf_[ni][2*cc+1] = (short)(u >> 16);
                } else {
                    bf_[ni][2*cc]   = (short)f2bf(wF[base]);
                    bf_[ni][2*cc+1] = (short)f2bf(wF[base+1]);
                }
                base += 2*dl;
            }
        }
        #pragma unroll
        for (int mi = 0; mi < 2; ++mi)
            #pragma unroll
            for (int ni = 0; ni < 4; ++ni)
                acc[mi][ni] = __builtin_amdgcn_mfma_f32_16x16x32_bf16(af[mi], bf_[ni], acc[mi][ni], 0,0,0);
    }
    #pragma unroll
    for (int mi = 0; mi < 2; ++mi)
        #pragma unroll
        for (int ni = 0; ni < 4; ++ni)
            #pragma unroll
            for (int r = 0; r < 4; ++r){
                int b = wv2*32 + mi*16 + kg*4 + r;
                int o = ob*64 + ni*16 + mr;
                unsafeAtomicAdd(outS + (d*128 + b)*256 + o, acc[mi][ni][r]);
            }
}
__global__ __launch_bounds__(256) void tail_k(const int* __restrict__ flag,
        const unsigned short* __restrict__ Ain, const void* __restrict__ wv,
        float* __restrict__ outS, int dl, int ksplit){
    if (*flag) tail_impl<true >(Ain, wv, outS, dl, ksplit);
    else       tail_impl<false>(Ain, wv, outS, dl, ksplit);
}

// ---------------------------------------------------------------------------
// Finalize: A_{l+1}[i] = bf16(relu(S_l[i]) / 16)
__global__ __launch_bounds__(256) void fin_kernel(const float* __restrict__ S,
        unsigned short* __restrict__ A, int n){
    int i = (blockIdx.x*256 + threadIdx.x)*4;
    if (i + 3 < n){
        float4 v = *(const float4*)(S + i);
        unsigned short r0 = f2bf(fmaxf(v.x,0.f)*0.0625f);
        unsigned short r1 = f2bf(fmaxf(v.y,0.f)*0.0625f);
        unsigned short r2 = f2bf(fmaxf(v.z,0.f)*0.0625f);
        unsigned short r3 = f2bf(fmaxf(v.w,0.f)*0.0625f);
        unsigned int lo = (unsigned int)r0 | ((unsigned int)r1 << 16);
        unsigned int hi = (unsigned int)r2 | ((unsigned int)r3 << 16);
        uint2 u; u.x = lo; u.y = hi;
        *(uint2*)(A + i) = u;
    }
}

// ---------------------------------------------------------------------------
template<bool BF>
__device__ __forceinline__ void epi_impl(const float* __restrict__ S9, const void* __restrict__ beta,
                                         void* __restrict__ out){
    int b = blockIdx.x;
    int lane = threadIdx.x;
    float accv[OUT_];
    #pragma unroll
    for (int o = 0; o < OUT_; ++o) accv[o] = 0.f;
    for (int h = lane; h < 256; h += 64){
        float y = fmaxf(S9[b*256 + h], 0.f) * 0.0625f;
        #pragma unroll
        for (int o = 0; o < OUT_; ++o){
            float be = BF ? bf2f(((const unsigned short*)beta)[h*OUT_ + o])
                          : ((const float*)beta)[h*OUT_ + o];
            accv[o] += y * be;
        }
    }
    #pragma unroll
    for (int off = 32; off > 0; off >>= 1){
        #pragma unroll
        for (int o = 0; o < OUT_; ++o)
            accv[o] += __shfl_down(accv[o], off, 64);
    }
    if (lane == 0){
        #pragma unroll
        for (int o = 0; o < OUT_; ++o){
            float v = accv[o] * (1.f/256.f);
            if (BF) ((unsigned short*)out)[b*OUT_ + o] = f2bf(v);
            else    ((float*)out)[b*OUT_ + o] = v;
        }
    }
}
__global__ void epi_kernel(const int* __restrict__ flag, const float* __restrict__ S9,
                           const void* __restrict__ beta, void* __restrict__ out){
    if (*flag) epi_impl<true>(S9, beta, out);
    else       epi_impl<false>(S9, beta, out);
}

// ---------------------------------------------------------------------------
extern "C" void kernel_launch(void* const* d_in, const int* in_sizes, int n_in,
                              void* d_out, int out_size, void* d_ws, size_t ws_size,
                              hipStream_t stream) {
    (void)in_sizes; (void)n_in; (void)out_size; (void)ws_size;
    char* wsb = (char*)d_ws;
    int* flag = (int*)wsb;
    char* base1 = wsb + 512;                  // 33.55 MB region: A1, then S3..S9 + A3..A9
    // S slots (fp32), contiguous from base1 (memset covers S3..S9 = 16,646,144 B)
    float* S3 = (float*)(base1);
    float* S4 = (float*)(base1 + 8388608);
    float* S5 = (float*)(base1 + 12582912);
    float* S6 = (float*)(base1 + 14680064);
    float* S7 = (float*)(base1 + 15728640);
    float* S8 = (float*)(base1 + 16252928);
    float* S9 = (float*)(base1 + 16515072);
    // A slots (bf16) after S region
    unsigned short* A3 = (unsigned short*)(base1 + 16646144);
    unsigned short* A4 = (unsigned short*)(base1 + 25034752);
    unsigned short* A5 = (unsigned short*)(base1 + 29229056);
    unsigned short* A6 = (unsigned short*)(base1 + 31326208);
    unsigned short* A7 = (unsigned short*)(base1 + 32374784);
    unsigned short* A8 = (unsigned short*)(base1 + 32899072);
    unsigned short* A9 = (unsigned short*)(base1 + 33161216);
    unsigned short* A1 = (unsigned short*)(base1);              // dies after l1
    unsigned short* A2 = (unsigned short*)(wsb + 512 + 33554432); // 16.78 MB

    probe_kernel<<<1, 256, 0, stream>>>((const unsigned int*)d_in[0], flag);
    l0_kernel<<<512, 256, 0, stream>>>(flag, d_in[0], d_in[1], A1);

    // l1: dl=256, dg=16, ks=1, direct -> A2.  grid = 1*16*8*4 = 512
    layer3_k<4,false><<<512, 256, 0, stream>>>(flag, A1, d_in[2], A2, 256, 16, 16);
    // A1 dead: zero S3..S9 for atomic layers
    hipMemsetAsync(base1, 0, 16646144, stream);
    // l2: dl=128, dg=8, ks=1, direct -> A3.  grid = 256
    layer3_k<4,false><<<256, 256, 0, stream>>>(flag, A2, d_in[3], A3, 128, 8, 16);
    // l3: dl=64, dg=4, ks=2 -> S3.  grid = 2*4*8*4 = 256
    layer3_k<4,true ><<<256, 256, 0, stream>>>(flag, A3, d_in[4], S3, 64, 4, 8);
    fin_kernel<<<2048, 256, 0, stream>>>(S3, A4, 2097152);
    // l4: dl=32, dg=2, ks=4 -> S4.  grid = 4*2*8*4 = 256
    layer3_k<4,true ><<<256, 256, 0, stream>>>(flag, A4, d_in[5], S4, 32, 2, 4);
    fin_kernel<<<1024, 256, 0, stream>>>(S4, A5, 1048576);
    // l5: dl=16, dg=1, ks=8 -> S5.  grid = 8*1*8*4 = 256
    layer3_k<4,true ><<<256, 256, 0, stream>>>(flag, A5, d_in[6], S5, 16, 1, 2);
    fin_kernel<<<512, 256, 0, stream>>>(S5, A6, 524288);
    // l6: dl=8, DT=8, dg=1, ks=8 -> S6.  grid = 256
    layer3_k<2,true ><<<256, 256, 0, stream>>>(flag, A6, d_in[7], S6, 8, 1, 2);
    fin_kernel<<<256, 256, 0, stream>>>(S6, A7, 262144);
    // l7: dl=4, DT=4, dg=1, ks=8 -> S7.  grid = 256
    layer3_k<1,true ><<<256, 256, 0, stream>>>(flag, A7, d_in[8], S7, 4, 1, 2);
    fin_kernel<<<128, 256, 0, stream>>>(S7, A8, 131072);
    // l8, l9: tail
    tail_k<<<128, 256, 0, stream>>>(flag, A8, d_in[9], S8, 2, 16);
    fin_kernel<<<64, 256, 0, stream>>>(S8, A9, 65536);
    tail_k<<<64, 256, 0, stream>>>(flag, A9, d_in[10], S9, 1, 16);
    epi_kernel<<<128, 64, 0, stream>>>(flag, S9, d_in[11], d_out);
}